// Round 3
// baseline (298.473 us; speedup 1.0000x reference)
//
#include <hip/hip_runtime.h>
#include <hip/hip_bf16.h>
#include <math.h>

// Compress (t,y) into NBINS bins of sufficient statistics (fp32, 28 KB), then
// run the entire Gauss-Newton solve (incl. Armijo line search) in ONE block,
// reconstructing every reduction  sum t^p e^{-lam t}, sum y t^p e^{-lam t}
// from a 3rd-order Taylor expansion about each bin center (~1e-9 rel error).
// OUTPUT IS FLOAT32 (reference returns fp32) — this was the R1/R2 bug.

#define NBINS 1024
#define NST   7
#define TMAXF 5.0f
#define BIN_BLOCKS  256
#define BIN_THREADS 256
#define ST  256                 // solver threads
#define NW  (ST / 64)           // waves in solver block
#define BPT (NBINS / ST)        // bins per solver thread

// ---------------------------------------------------------------- zero stats
__global__ void zero_stats(float* __restrict__ s) {
  int i = blockIdx.x * blockDim.x + threadIdx.x;
  if (i < NST * NBINS) s[i] = 0.0f;
}

// ---------------------------------------------------------------- binning
// stat-major layout stat*NBINS+b:
//   0:n  1:sum d  2:sum d^2  3:sum d^3  4:sum y  5:sum y d  6:sum y d^2
// d = t - c_b, c_b = (b+0.5)*h computed in fp32 (matched exactly in solver).
__global__ void bin_kernel(const float* __restrict__ y, const float* __restrict__ t,
                           int n, float* __restrict__ stats) {
  __shared__ float sb[NST * NBINS];   // 28 KB
  for (int i = threadIdx.x; i < NST * NBINS; i += blockDim.x) sb[i] = 0.0f;
  __syncthreads();
  int stride = gridDim.x * blockDim.x;
  for (int i = blockIdx.x * blockDim.x + threadIdx.x; i < n; i += stride) {
    float ti = t[i], yi = y[i];
    int b = (int)(ti * ((float)NBINS / TMAXF));
    b = b < 0 ? 0 : (b > NBINS - 1 ? NBINS - 1 : b);
    float c  = (b + 0.5f) * (TMAXF / (float)NBINS);
    float d  = ti - c;
    float d2 = d * d;
    atomicAdd(&sb[0 * NBINS + b], 1.0f);
    atomicAdd(&sb[1 * NBINS + b], d);
    atomicAdd(&sb[2 * NBINS + b], d2);
    atomicAdd(&sb[3 * NBINS + b], d2 * d);
    atomicAdd(&sb[4 * NBINS + b], yi);
    atomicAdd(&sb[5 * NBINS + b], yi * d);
    atomicAdd(&sb[6 * NBINS + b], yi * d2);
  }
  __syncthreads();
  for (int i = threadIdx.x; i < NST * NBINS; i += blockDim.x) {
    float v = sb[i];
    if (v != 0.0f) atomicAdd(&stats[i], v);
  }
}

// ---------------------------------------------------------------- solver
__device__ __forceinline__ double sp_d(double u) { return log1p(exp(u)); }

__device__ __forceinline__ double wred(double v) {
  for (int off = 32; off > 0; off >>= 1) v += __shfl_down(v, off, 64);
  return v;
}

template <bool FUSED>
__global__ __launch_bounds__(ST)
void gn_kernel(const float* __restrict__ stats_g,
               const float* __restrict__ yv, const float* __restrict__ tv, int n,
               const float* __restrict__ log_mu_p,
               const float* __restrict__ x_init_p,
               float* __restrict__ out) {
  const int tid  = threadIdx.x;
  const int lane = tid & 63;
  const int wv   = tid >> 6;

  __shared__ float sbin[NST * NBINS];   // used only in FUSED path (28 KB)
  const float* stats = stats_g;
  if (FUSED) {
    for (int i = tid; i < NST * NBINS; i += ST) sbin[i] = 0.0f;
    __syncthreads();
    for (int i = tid; i < n; i += ST) {
      float ti = tv[i], yi = yv[i];
      int b = (int)(ti * ((float)NBINS / TMAXF));
      b = b < 0 ? 0 : (b > NBINS - 1 ? NBINS - 1 : b);
      float c  = (b + 0.5f) * (TMAXF / (float)NBINS);
      float d  = ti - c;
      float d2 = d * d;
      atomicAdd(&sbin[0 * NBINS + b], 1.0f);
      atomicAdd(&sbin[1 * NBINS + b], d);
      atomicAdd(&sbin[2 * NBINS + b], d2);
      atomicAdd(&sbin[3 * NBINS + b], d2 * d);
      atomicAdd(&sbin[4 * NBINS + b], yi);
      atomicAdd(&sbin[5 * NBINS + b], yi * d);
      atomicAdd(&sbin[6 * NBINS + b], yi * d2);
    }
    __syncthreads();
    stats = sbin;
  }

  // per-thread bin stats in registers
  double bn[BPT], b1[BPT], b2[BPT], b3[BPT], by[BPT], by1[BPT], by2[BPT], bc[BPT];
  for (int j = 0; j < BPT; ++j) {
    int b = tid + j * ST;
    bn[j]  = (double)stats[0 * NBINS + b];
    b1[j]  = (double)stats[1 * NBINS + b];
    b2[j]  = (double)stats[2 * NBINS + b];
    b3[j]  = (double)stats[3 * NBINS + b];
    by[j]  = (double)stats[4 * NBINS + b];
    by1[j] = (double)stats[5 * NBINS + b];
    by2[j] = (double)stats[6 * NBINS + b];
    bc[j]  = (double)((b + 0.5f) * (TMAXF / (float)NBINS));
  }

  __shared__ double s_u[4], s_du[4];
  __shared__ double s_w[13][NW];
  __shared__ double s_gd, s_loss, s_step;
  __shared__ int s_done, s_lsdone, s_k, s_bad;

  // ---- canary A: verify total count == n ----
  {
    double nt = 0.0;
    for (int j = 0; j < BPT; ++j) nt += bn[j];
    nt = wred(nt);
    if (lane == 0) s_w[0][wv] = nt;
    __syncthreads();
    if (tid == 0) {
      double tot = 0.0;
      for (int w = 0; w < NW; ++w) tot += s_w[0][w];
      s_bad = (fabs(tot - (double)n) > (double)n * 1e-3 + 1.0) ? 1 : 0;
    }
    __syncthreads();
    if (s_bad) {
      if (tid == 0)
        for (int j = 0; j < 4; ++j) out[j] = 20.0f + (float)j;
      return;
    }
  }

  double mu = 0.0;
  if (tid == 0) {
    mu = exp((double)log_mu_p[0]);
    for (int j = 0; j < 4; ++j) {
      double v = (double)x_init_p[j];
      if (v < 1e-3) v = 1e-3;                 // clip(x_init, 1e-3)
      s_u[j] = log(exp(v) - 1.0 + 1e-8);      // inv_softplus
    }
    s_done = 0;
  }
  __syncthreads();

  for (int iter = 0; iter < 300; ++iter) {
    if (s_done) break;

    // -------- Phase A: 13-moment pass at current u --------
    double c0 = sp_d(s_u[0]), c1 = sp_d(s_u[1]);
    double l0 = sp_d(s_u[2]), l1 = sp_d(s_u[3]);
    double M[3] = {2.0 * l0, l0 + l1, 2.0 * l1};
    double acc[13];
    for (int k = 0; k < 13; ++k) acc[k] = 0.0;
    for (int j = 0; j < BPT; ++j) {
      double c  = bc[j];
      double E0 = exp(-l0 * c), E1 = exp(-l1 * c);
      double A[3] = {E0 * E0, E0 * E1, E1 * E1};
#pragma unroll
      for (int q = 0; q < 3; ++q) {
        double m  = M[q];
        double q0 = bn[j] + m * (-b1[j] + m * (0.5 * b2[j] - m * (1.0 / 6.0) * b3[j]));
        double q1 = b1[j] + m * (-b2[j] + m * 0.5 * b3[j]);
        double q2 = b2[j] - m * b3[j];
        acc[q * 3 + 0] += A[q] * q0;
        acc[q * 3 + 1] += A[q] * (c * q0 + q1);
        acc[q * 3 + 2] += A[q] * (c * (c * q0 + 2.0 * q1) + q2);
      }
      double r0 = by[j] + l0 * (-by1[j] + 0.5 * l0 * by2[j]);
      double r1 = by1[j] - l0 * by2[j];
      acc[9]  += E0 * r0;
      acc[10] += E0 * (c * r0 + r1);
      r0 = by[j] + l1 * (-by1[j] + 0.5 * l1 * by2[j]);
      r1 = by1[j] - l1 * by2[j];
      acc[11] += E1 * r0;
      acc[12] += E1 * (c * r0 + r1);
    }
    for (int k = 0; k < 13; ++k) {
      double v = wred(acc[k]);
      if (lane == 0) s_w[k][wv] = v;
    }
    __syncthreads();

    // -------- Phase B: thread 0 builds H/grad, solves 4x4 --------
    if (tid == 0) {
      double r[13];
      for (int k = 0; k < 13; ++k) {
        double s = 0.0;
        for (int w = 0; w < NW; ++w) s += s_w[k][w];
        r[k] = s;
      }
      double Sa = r[0],  T1a = r[1],  T2a = r[2];
      double Sab= r[3],  T1ab= r[4],  T2ab= r[5];
      double Sb = r[6],  T1b = r[7],  T2b = r[8];
      double Y0a= r[9],  Y1a = r[10], Y0b = r[11], Y1b = r[12];

      double x[4] = {c0, c1, l0, l1};
      double sd[4];
      for (int j = 0; j < 4; ++j) sd[j] = 1.0 / (1.0 + exp(-s_u[j]));

      double Jxx[4][4];
      Jxx[0][0] = Sa;            Jxx[0][1] = Sab;
      Jxx[0][2] = -c0 * T1a;     Jxx[0][3] = -c1 * T1ab;
      Jxx[1][1] = Sb;            Jxx[1][2] = -c0 * T1ab;  Jxx[1][3] = -c1 * T1b;
      Jxx[2][2] = c0 * c0 * T2a; Jxx[2][3] = c0 * c1 * T2ab;
      Jxx[3][3] = c1 * c1 * T2b;
      for (int i = 1; i < 4; ++i)
        for (int j = 0; j < i; ++j) Jxx[i][j] = Jxx[j][i];

      double Jtr[4];
      Jtr[0] = Y0a - c0 * Sa - c1 * Sab;
      Jtr[1] = Y0b - c0 * Sab - c1 * Sb;
      Jtr[2] = -c0 * (Y1a - c0 * T1a - c1 * T1ab);
      Jtr[3] = -c1 * (Y1b - c0 * T1ab - c1 * T1b);

      double g[4];
      for (int i = 0; i < 4; ++i) g[i] = -sd[i] * Jtr[i] + mu * x[i] * sd[i];

      double H[4][5];
      for (int i = 0; i < 4; ++i) {
        for (int j = 0; j < 4; ++j) H[i][j] = sd[i] * sd[j] * Jxx[i][j];
        H[i][i] += mu + 1e-7;
        H[i][4] = -g[i];
      }
      for (int col = 0; col < 4; ++col) {                // pivoted elimination
        int p = col; double best = fabs(H[col][col]);
        for (int rr = col + 1; rr < 4; ++rr) {
          double a = fabs(H[rr][col]);
          if (a > best) { best = a; p = rr; }
        }
        if (p != col)
          for (int j2 = col; j2 < 5; ++j2) {
            double tmp = H[col][j2]; H[col][j2] = H[p][j2]; H[p][j2] = tmp;
          }
        double inv = 1.0 / H[col][col];
        for (int rr = col + 1; rr < 4; ++rr) {
          double f = H[rr][col] * inv;
          for (int j2 = col; j2 < 5; ++j2) H[rr][j2] -= f * H[col][j2];
        }
      }
      double du[4];
      for (int i = 3; i >= 0; --i) {
        double s = H[i][4];
        for (int j2 = i + 1; j2 < 4; ++j2) s -= H[i][j2] * du[j2];
        du[i] = s / H[i][i];
      }
      double gd = g[0]*du[0] + g[1]*du[1] + g[2]*du[2] + g[3]*du[3];
      // loss with the constant sum(y^2) dropped (cancels in Armijo compare)
      double L = -2.0*c0*Y0a - 2.0*c1*Y0b
               + c0*c0*Sa + 2.0*c0*c1*Sab + c1*c1*Sb;
      double loss = L + mu * (x[0]*x[0] + x[1]*x[1] + x[2]*x[2] + x[3]*x[3]);
      for (int j = 0; j < 4; ++j) s_du[j] = du[j];
      s_gd = gd; s_loss = loss;
      s_step = 1.0; s_k = 0; s_lsdone = 0;
    }
    __syncthreads();

    // -------- Phase C: Armijo backtracking line search --------
    while (true) {
      if (s_lsdone) break;
      double st = s_step;
      double xp[4];
      for (int j = 0; j < 4; ++j) xp[j] = sp_d(s_u[j] + st * s_du[j]);
      double c0p = xp[0], c1p = xp[1], l0p = xp[2], l1p = xp[3];
      double mm[3] = {2.0 * l0p, l0p + l1p, 2.0 * l1p};
      double a5[5] = {0, 0, 0, 0, 0};
      for (int j = 0; j < BPT; ++j) {
        double c  = bc[j];
        double E0 = exp(-l0p * c), E1 = exp(-l1p * c);
        double A[3] = {E0 * E0, E0 * E1, E1 * E1};
#pragma unroll
        for (int q = 0; q < 3; ++q) {
          double m  = mm[q];
          double q0 = bn[j] + m * (-b1[j] + m * (0.5 * b2[j] - m * (1.0 / 6.0) * b3[j]));
          a5[q] += A[q] * q0;
        }
        double r0 = by[j] + l0p * (-by1[j] + 0.5 * l0p * by2[j]);
        a5[3] += E0 * r0;
        r0 = by[j] + l1p * (-by1[j] + 0.5 * l1p * by2[j]);
        a5[4] += E1 * r0;
      }
      for (int k = 0; k < 5; ++k) {
        double v = wred(a5[k]);
        if (lane == 0) s_w[k][wv] = v;
      }
      __syncthreads();
      if (tid == 0) {
        double rr[5];
        for (int k = 0; k < 5; ++k) {
          double s = 0.0;
          for (int w = 0; w < NW; ++w) s += s_w[k][w];
          rr[k] = s;
        }
        double Lnew = -2.0*c0p*rr[3] - 2.0*c1p*rr[4]
                    + c0p*c0p*rr[0] + 2.0*c0p*c1p*rr[1] + c1p*c1p*rr[2];
        double loss_new = Lnew + mu * (c0p*c0p + c1p*c1p + l0p*l0p + l1p*l1p);
        bool ok = (loss_new <= s_loss - 1e-4 * st * s_gd);   // NaN -> reject
        s_step = ok ? st : st * 0.5;
        int k2 = s_k + 1;
        s_k = k2;
        if (ok || k2 >= 25) s_lsdone = 1;
      }
      __syncthreads();
    }

    // -------- Phase D: update u, convergence check --------
    if (tid == 0) {
      double st  = s_step;
      double nrm = sqrt(s_du[0]*s_du[0] + s_du[1]*s_du[1]
                      + s_du[2]*s_du[2] + s_du[3]*s_du[3]);
      for (int j = 0; j < 4; ++j) s_u[j] += st * s_du[j];
      if (st * nrm < 1e-9) s_done = 1;
    }
    __syncthreads();
  }

  if (tid == 0) {
    float o[4]; bool bad = false;
    for (int j = 0; j < 4; ++j) {
      double v = sp_d(s_u[j]);
      if (!isfinite(v)) bad = true;
      o[j] = (float)v;
    }
    if (bad) {
      for (int j = 0; j < 4; ++j) out[j] = 50.0f + (float)j;
    } else {
      for (int j = 0; j < 4; ++j) out[j] = o[j];
    }
  }
}

// ---------------------------------------------------------------- launch
extern "C" void kernel_launch(void* const* d_in, const int* in_sizes, int n_in,
                              void* d_out, int out_size, void* d_ws, size_t ws_size,
                              hipStream_t stream) {
  const float* log_mu = (const float*)d_in[0];
  const float* y      = (const float*)d_in[1];
  const float* t      = (const float*)d_in[2];
  const float* x_init = (const float*)d_in[3];
  float* out = (float*)d_out;          // reference output dtype is FLOAT32
  int n = in_sizes[1];

  const size_t need = (size_t)NST * NBINS * sizeof(float);   // 28 KB
  if (d_ws != nullptr && ws_size >= need) {
    float* stats = (float*)d_ws;
    zero_stats<<<(NST * NBINS + 255) / 256, 256, 0, stream>>>(stats);
    bin_kernel<<<BIN_BLOCKS, BIN_THREADS, 0, stream>>>(y, t, n, stats);
    gn_kernel<false><<<1, ST, 0, stream>>>(stats, nullptr, nullptr, n,
                                           log_mu, x_init, out);
  } else {
    gn_kernel<true><<<1, ST, 0, stream>>>(nullptr, y, t, n,
                                          log_mu, x_init, out);
  }
}

// Round 4
// 276.145 us; speedup vs baseline: 1.0809x; 1.0809x over previous
//
#include <hip/hip_runtime.h>
#include <hip/hip_bf16.h>
#include <math.h>

// Binned-sufficient-statistics Gauss/Newton solver.
//  - bin_kernel: compress (t,y) into 1024 bins x 7 fp32 stats (28 KB).
//  - gn_kernel: full-Newton (exact Hessian of the binned surrogate, GN
//    fallback) with Armijo line search, single block, fp64, fast inline
//    exp/log. Converges to the same surrogate minimizer as GN/tol=1e-9.

#define NBINS 1024
#define NST   7
#define TMAXF 5.0f
#define BIN_BLOCKS  256
#define BIN_THREADS 256
#define ST  256
#define NW  (ST / 64)
#define BPT (NBINS / ST)
#define NACC 15

// ---------------------------------------------------------------- fast fp64 math
__device__ __forceinline__ double fexp(double x) {
  x = fmin(fmax(x, -708.0), 700.0);
  const double L2E   = 1.4426950408889634074;
  const double LN2HI = 6.93147180369123816490e-01;
  const double LN2LO = 1.90821492927058770002e-10;
  double fn = rint(x * L2E);
  double r  = fma(-fn, LN2HI, x);
  r = fma(-fn, LN2LO, r);
  double p = 2.505210838544172e-8;            // 1/11!
  p = fma(p, r, 2.755731922398589e-7);
  p = fma(p, r, 2.7557319223985893e-6);
  p = fma(p, r, 2.48015873015873e-5);
  p = fma(p, r, 1.984126984126984e-4);
  p = fma(p, r, 1.3888888888888889e-3);
  p = fma(p, r, 8.333333333333333e-3);
  p = fma(p, r, 4.1666666666666664e-2);
  p = fma(p, r, 1.6666666666666666e-1);
  p = fma(p, r, 0.5);
  p = fma(p, r, 1.0);
  p = fma(p, r, 1.0);
  long long n = (long long)fn;
  double s = __longlong_as_double((n + 1023LL) << 52);
  return p * s;
}

__device__ __forceinline__ double flog_ge1(double w) {  // w >= 1 (inf-safe)
  long long bits = __double_as_longlong(w);
  int k = (int)((bits >> 52) & 0x7FF) - 1023;
  double m = __longlong_as_double((bits & 0xFFFFFFFFFFFFFLL) | 0x3FF0000000000000LL);
  if (m > 1.4142135623730951) { m *= 0.5; k += 1; }
  double t  = (m - 1.0) / (m + 1.0);
  double t2 = t * t;
  double p = 1.0 / 13.0;
  p = fma(p, t2, 1.0 / 11.0);
  p = fma(p, t2, 1.0 / 9.0);
  p = fma(p, t2, 1.0 / 7.0);
  p = fma(p, t2, 0.2);
  p = fma(p, t2, 1.0 / 3.0);
  p = fma(p, t2, 1.0);
  p = 2.0 * t * p;
  return fma((double)k, 6.93147180559945309417e-01, p);
}

__device__ __forceinline__ double sp_fast(double u)  { return flog_ge1(1.0 + fexp(u)); }
__device__ __forceinline__ double sig_fast(double u) { return 1.0 / (1.0 + fexp(-u)); }

__device__ __forceinline__ double wred(double v) {
  for (int off = 32; off > 0; off >>= 1) v += __shfl_down(v, off, 64);
  return v;
}

// ---------------------------------------------------------------- binning
__global__ void zero_stats(float* __restrict__ s) {
  int i = blockIdx.x * blockDim.x + threadIdx.x;
  if (i < NST * NBINS) s[i] = 0.0f;
}

__device__ __forceinline__ void bin_point(float* sb, float ti, float yi) {
  int b = (int)(ti * ((float)NBINS / TMAXF));
  b = b < 0 ? 0 : (b > NBINS - 1 ? NBINS - 1 : b);
  float c  = (b + 0.5f) * (TMAXF / (float)NBINS);
  float d  = ti - c;
  float d2 = d * d;
  atomicAdd(&sb[0 * NBINS + b], 1.0f);
  atomicAdd(&sb[1 * NBINS + b], d);
  atomicAdd(&sb[2 * NBINS + b], d2);
  atomicAdd(&sb[3 * NBINS + b], d2 * d);
  atomicAdd(&sb[4 * NBINS + b], yi);
  atomicAdd(&sb[5 * NBINS + b], yi * d);
  atomicAdd(&sb[6 * NBINS + b], yi * d2);
}

template <bool PARTIALS>
__global__ void bin_kernel(const float* __restrict__ y, const float* __restrict__ t,
                           int n, float* __restrict__ dst) {
  __shared__ float sb[NST * NBINS];
  for (int i = threadIdx.x; i < NST * NBINS; i += blockDim.x) sb[i] = 0.0f;
  __syncthreads();
  int gtid = blockIdx.x * blockDim.x + threadIdx.x;
  int nt   = gridDim.x * blockDim.x;
  int nv   = n >> 2;
  const float4* t4 = (const float4*)t;
  const float4* y4 = (const float4*)y;
  for (int i = gtid; i < nv; i += nt) {
    float4 tv = t4[i], yv = y4[i];
    bin_point(sb, tv.x, yv.x);
    bin_point(sb, tv.y, yv.y);
    bin_point(sb, tv.z, yv.z);
    bin_point(sb, tv.w, yv.w);
  }
  for (int i = (nv << 2) + gtid; i < n; i += nt) bin_point(sb, t[i], y[i]);
  __syncthreads();
  if (PARTIALS) {
    float* p = dst + (size_t)blockIdx.x * (NST * NBINS);
    for (int i = threadIdx.x; i < NST * NBINS; i += blockDim.x) p[i] = sb[i];
  } else {
    for (int i = threadIdx.x; i < NST * NBINS; i += blockDim.x) {
      float v = sb[i];
      if (v != 0.0f) atomicAdd(&dst[i], v);
    }
  }
}

__global__ void reduce_kernel(const float* __restrict__ partials,
                              float* __restrict__ stats) {
  int j = blockIdx.x * blockDim.x + threadIdx.x;
  if (j < NST * NBINS) {
    float s = 0.0f;
    for (int k = 0; k < BIN_BLOCKS; ++k)
      s += partials[(size_t)k * (NST * NBINS) + j];
    stats[j] = s;
  }
}

// ---------------------------------------------------------------- 4x4 solve
__device__ __forceinline__ void solve4(double H[4][5], double du[4]) {
  for (int col = 0; col < 4; ++col) {
    int p = col; double best = fabs(H[col][col]);
    for (int rr = col + 1; rr < 4; ++rr) {
      double a = fabs(H[rr][col]);
      if (a > best) { best = a; p = rr; }
    }
    if (p != col)
      for (int j = col; j < 5; ++j) {
        double tmp = H[col][j]; H[col][j] = H[p][j]; H[p][j] = tmp;
      }
    double inv = 1.0 / H[col][col];
    for (int rr = col + 1; rr < 4; ++rr) {
      double f = H[rr][col] * inv;
      for (int j = col; j < 5; ++j) H[rr][j] -= f * H[col][j];
    }
  }
  for (int i = 3; i >= 0; --i) {
    double s = H[i][4];
    for (int j = i + 1; j < 4; ++j) s -= H[i][j] * du[j];
    du[i] = s / H[i][i];
  }
}

// ---------------------------------------------------------------- solver
template <bool FUSED>
__global__ __launch_bounds__(ST)
void gn_kernel(const float* __restrict__ stats_g,
               const float* __restrict__ yv, const float* __restrict__ tv, int n,
               const float* __restrict__ log_mu_p,
               const float* __restrict__ x_init_p,
               float* __restrict__ out) {
  const int tid  = threadIdx.x;
  const int lane = tid & 63;
  const int wv   = tid >> 6;

  __shared__ float sbin[FUSED ? NST * NBINS : 1];
  const float* stats = stats_g;
  if (FUSED) {
    for (int i = tid; i < NST * NBINS; i += ST) sbin[i] = 0.0f;
    __syncthreads();
    for (int i = tid; i < n; i += ST) bin_point(sbin, tv[i], yv[i]);
    __syncthreads();
    stats = sbin;
  }

  // per-thread bin stats in registers; bins b = tid + j*ST, c exact in fp32
  double bn[BPT], b1[BPT], b2[BPT], b3[BPT], by[BPT], by1[BPT], by2[BPT], bc[BPT];
  for (int j = 0; j < BPT; ++j) {
    int b = tid + j * ST;
    bn[j]  = (double)stats[0 * NBINS + b];
    b1[j]  = (double)stats[1 * NBINS + b];
    b2[j]  = (double)stats[2 * NBINS + b];
    b3[j]  = (double)stats[3 * NBINS + b];
    by[j]  = (double)stats[4 * NBINS + b];
    by1[j] = (double)stats[5 * NBINS + b];
    by2[j] = (double)stats[6 * NBINS + b];
    bc[j]  = (double)((b + 0.5f) * (TMAXF / (float)NBINS));
  }
  const double c_base = bc[0];          // c_{j+1} = c_j + 1.25 exactly

  __shared__ double s_u[4], s_x[4], s_du[4], s_R[2];
  __shared__ double s_w[NACC][NW];
  __shared__ double s_gd, s_loss, s_step;
  __shared__ int s_done, s_lsdone, s_k, s_bad;

  // ---- canary: total count == n ----
  {
    double nt = 0.0;
    for (int j = 0; j < BPT; ++j) nt += bn[j];
    nt = wred(nt);
    if (lane == 0) s_w[0][wv] = nt;
    __syncthreads();
    if (tid == 0) {
      double tot = 0.0;
      for (int w = 0; w < NW; ++w) tot += s_w[0][w];
      s_bad = (fabs(tot - (double)n) > (double)n * 1e-3 + 1.0) ? 1 : 0;
    }
    __syncthreads();
    if (s_bad) {
      if (tid == 0) for (int j = 0; j < 4; ++j) out[j] = 20.0f + (float)j;
      return;
    }
  }

  double mu = 0.0;                      // live only in tid 0
  if (tid == 0) {
    mu = exp((double)log_mu_p[0]);
    for (int j = 0; j < 4; ++j) {
      double v = (double)x_init_p[j];
      if (v < 1e-3) v = 1e-3;                 // clip(x_init, 1e-3)
      double u = log(exp(v) - 1.0 + 1e-8);    // inv_softplus
      s_u[j] = u;
      s_x[j] = sp_fast(u);
    }
    s_R[0] = fexp(-1.25 * s_x[2]);
    s_R[1] = fexp(-1.25 * s_x[3]);
    s_done = 0;
  }
  __syncthreads();

  for (int iter = 0; iter < 300; ++iter) {
    if (s_done) break;

    // ---- Phase A: 15-moment pass at current x ----
    double l0 = s_x[2], l1 = s_x[3];
    double R0 = s_R[0], R1 = s_R[1];
    double M[3] = {2.0 * l0, l0 + l1, 2.0 * l1};
    double acc[NACC];
    for (int k = 0; k < NACC; ++k) acc[k] = 0.0;
    double E0 = fexp(-l0 * c_base);
    double E1 = fexp(-l1 * c_base);
    for (int j = 0; j < BPT; ++j) {
      double c = bc[j];
      double A[3] = {E0 * E0, E0 * E1, E1 * E1};
#pragma unroll
      for (int q = 0; q < 3; ++q) {
        double m  = M[q];
        double q0 = bn[j] + m * (-b1[j] + m * (0.5 * b2[j] - m * (1.0 / 6.0) * b3[j]));
        double q1 = b1[j] + m * (-b2[j] + m * 0.5 * b3[j]);
        double q2 = b2[j] - m * b3[j];
        acc[q * 3 + 0] += A[q] * q0;
        acc[q * 3 + 1] += A[q] * (c * q0 + q1);
        acc[q * 3 + 2] += A[q] * (c * (c * q0 + 2.0 * q1) + q2);
      }
      {
        double r0 = by[j] + l0 * (-by1[j] + 0.5 * l0 * by2[j]);
        double r1 = by1[j] - l0 * by2[j];
        acc[9]  += E0 * r0;
        acc[10] += E0 * (c * r0 + r1);
        acc[11] += E0 * (c * (c * r0 + 2.0 * r1) + by2[j]);
      }
      {
        double r0 = by[j] + l1 * (-by1[j] + 0.5 * l1 * by2[j]);
        double r1 = by1[j] - l1 * by2[j];
        acc[12] += E1 * r0;
        acc[13] += E1 * (c * r0 + r1);
        acc[14] += E1 * (c * (c * r0 + 2.0 * r1) + by2[j]);
      }
      E0 *= R0; E1 *= R1;
    }
    for (int k = 0; k < NACC; ++k) {
      double v = wred(acc[k]);
      if (lane == 0) s_w[k][wv] = v;
    }
    __syncthreads();

    // ---- Phase B: tid 0 — Newton (exact surrogate Hessian), GN fallback ----
    if (tid == 0) {
      double r[NACC];
      for (int k = 0; k < NACC; ++k) {
        double s = 0.0;
        for (int w = 0; w < NW; ++w) s += s_w[k][w];
        r[k] = s;
      }
      double Sa = r[0],  T1a = r[1],  T2a = r[2];
      double Sab= r[3],  T1ab= r[4],  T2ab= r[5];
      double Sb = r[6],  T1b = r[7],  T2b = r[8];
      double Y0a= r[9],  Y1a = r[10], Y2a = r[11];
      double Y0b= r[12], Y1b = r[13], Y2b = r[14];

      double c0 = s_x[0], c1 = s_x[1];
      double sd[4], spp[4];
      for (int j = 0; j < 4; ++j) {
        sd[j]  = sig_fast(s_u[j]);
        spp[j] = sd[j] * (1.0 - sd[j]);
      }

      // half-gradient in x-space
      double gx[4];
      gx[0] = -Y0a + c0 * Sa  + c1 * Sab;
      gx[1] = -Y0b + c0 * Sab + c1 * Sb;
      gx[2] = c0 * (Y1a - c0 * T1a  - c1 * T1ab);
      gx[3] = c1 * (Y1b - c0 * T1ab - c1 * T1b);
      double g[4];
      for (int i = 0; i < 4; ++i) g[i] = (gx[i] + mu * s_x[i]) * sd[i];

      // half-Hessian in x-space (exact for the surrogate)
      double Hx[4][4];
      Hx[0][0] = Sa;   Hx[0][1] = Sab;
      Hx[0][2] = Y1a - 2.0 * c0 * T1a - c1 * T1ab;
      Hx[0][3] = -c1 * T1ab;
      Hx[1][1] = Sb;   Hx[1][2] = -c0 * T1ab;
      Hx[1][3] = Y1b - c0 * T1ab - 2.0 * c1 * T1b;
      Hx[2][2] = -c0 * Y2a + 2.0 * c0 * c0 * T2a + c0 * c1 * T2ab;
      Hx[2][3] = c0 * c1 * T2ab;
      Hx[3][3] = -c1 * Y2b + c0 * c1 * T2ab + 2.0 * c1 * c1 * T2b;
      for (int i = 1; i < 4; ++i)
        for (int j = 0; j < i; ++j) Hx[i][j] = Hx[j][i];

      // u-space Newton system
      double H[4][5], du[4];
      for (int i = 0; i < 4; ++i) {
        for (int j = 0; j < 4; ++j) {
          double v = Hx[i][j] + (i == j ? mu : 0.0);
          H[i][j] = sd[i] * sd[j] * v;
        }
        H[i][i] += (gx[i] + mu * s_x[i]) * spp[i] + 1e-7;
        H[i][4] = -g[i];
      }
      solve4(H, du);
      double gd = g[0]*du[0] + g[1]*du[1] + g[2]*du[2] + g[3]*du[3];
      bool bad = !(isfinite(du[0]) && isfinite(du[1]) &&
                   isfinite(du[2]) && isfinite(du[3])) || !(gd < 0.0);
      if (bad) {   // GN fallback (guaranteed PD)
        double Jxx[4][4];
        Jxx[0][0] = Sa;            Jxx[0][1] = Sab;
        Jxx[0][2] = -c0 * T1a;     Jxx[0][3] = -c1 * T1ab;
        Jxx[1][1] = Sb;            Jxx[1][2] = -c0 * T1ab;  Jxx[1][3] = -c1 * T1b;
        Jxx[2][2] = c0 * c0 * T2a; Jxx[2][3] = c0 * c1 * T2ab;
        Jxx[3][3] = c1 * c1 * T2b;
        for (int i = 1; i < 4; ++i)
          for (int j = 0; j < i; ++j) Jxx[i][j] = Jxx[j][i];
        for (int i = 0; i < 4; ++i) {
          for (int j = 0; j < 4; ++j) H[i][j] = sd[i] * sd[j] * Jxx[i][j];
          H[i][i] += mu + 1e-7;
          H[i][4] = -g[i];
        }
        solve4(H, du);
        gd = g[0]*du[0] + g[1]*du[1] + g[2]*du[2] + g[3]*du[3];
        if (!(gd < 0.0)) {  // last-resort steepest descent
          for (int i = 0; i < 4; ++i) du[i] = -g[i];
          gd = -(g[0]*g[0] + g[1]*g[1] + g[2]*g[2] + g[3]*g[3]);
        }
      }
      double L = -2.0*c0*Y0a - 2.0*c1*Y0b
               + c0*c0*Sa + 2.0*c0*c1*Sab + c1*c1*Sb;
      double xs = s_x[0]*s_x[0] + s_x[1]*s_x[1] + s_x[2]*s_x[2] + s_x[3]*s_x[3];
      s_loss = L + mu * xs;
      for (int j = 0; j < 4; ++j) s_du[j] = du[j];
      s_gd = gd; s_step = 1.0; s_k = 0; s_lsdone = 0;
    }
    __syncthreads();

    // ---- Phase C: Armijo backtracking (+ state update on exit) ----
    while (true) {
      if (s_lsdone) break;
      double st = s_step;
      double xp[4];
      for (int j = 0; j < 4; ++j) xp[j] = sp_fast(s_u[j] + st * s_du[j]);
      double c0p = xp[0], c1p = xp[1], l0p = xp[2], l1p = xp[3];
      double Rp0 = fexp(-1.25 * l0p), Rp1 = fexp(-1.25 * l1p);
      double mm[3] = {2.0 * l0p, l0p + l1p, 2.0 * l1p};
      double a5[5] = {0, 0, 0, 0, 0};
      double F0 = fexp(-l0p * c_base);
      double F1 = fexp(-l1p * c_base);
      for (int j = 0; j < BPT; ++j) {
        double A[3] = {F0 * F0, F0 * F1, F1 * F1};
#pragma unroll
        for (int q = 0; q < 3; ++q) {
          double m  = mm[q];
          double q0 = bn[j] + m * (-b1[j] + m * (0.5 * b2[j] - m * (1.0 / 6.0) * b3[j]));
          a5[q] += A[q] * q0;
        }
        a5[3] += F0 * (by[j] + l0p * (-by1[j] + 0.5 * l0p * by2[j]));
        a5[4] += F1 * (by[j] + l1p * (-by1[j] + 0.5 * l1p * by2[j]));
        F0 *= Rp0; F1 *= Rp1;
      }
      for (int k = 0; k < 5; ++k) {
        double v = wred(a5[k]);
        if (lane == 0) s_w[k][wv] = v;
      }
      __syncthreads();
      if (tid == 0) {
        double rr[5];
        for (int k = 0; k < 5; ++k) {
          double s = 0.0;
          for (int w = 0; w < NW; ++w) s += s_w[k][w];
          rr[k] = s;
        }
        double Lnew = -2.0*c0p*rr[3] - 2.0*c1p*rr[4]
                    + c0p*c0p*rr[0] + 2.0*c0p*c1p*rr[1] + c1p*c1p*rr[2];
        double loss_new = Lnew + mu * (c0p*c0p + c1p*c1p + l0p*l0p + l1p*l1p);
        bool ok = (loss_new <= s_loss - 1e-4 * st * s_gd);   // NaN -> reject
        double nrm = sqrt(s_du[0]*s_du[0] + s_du[1]*s_du[1]
                        + s_du[2]*s_du[2] + s_du[3]*s_du[3]);
        if (ok) {
          for (int j = 0; j < 4; ++j) { s_u[j] += st * s_du[j]; s_x[j] = xp[j]; }
          s_R[0] = Rp0; s_R[1] = Rp1;
          if (st * nrm < 1e-9) s_done = 1;
          s_lsdone = 1;
        } else {
          double ns = st * 0.5;
          s_step = ns;
          int k2 = s_k + 1; s_k = k2;
          if (k2 >= 25) {   // forced exit: update with final halved step
            for (int j = 0; j < 4; ++j) {
              s_u[j] += ns * s_du[j];
              s_x[j]  = sp_fast(s_u[j]);
            }
            s_R[0] = fexp(-1.25 * s_x[2]);
            s_R[1] = fexp(-1.25 * s_x[3]);
            if (ns * nrm < 1e-9) s_done = 1;
            s_lsdone = 1;
          }
        }
      }
      __syncthreads();
    }
  }

  if (tid == 0) {
    bool bad = false;
    for (int j = 0; j < 4; ++j) if (!isfinite(s_x[j])) bad = true;
    for (int j = 0; j < 4; ++j)
      out[j] = bad ? (50.0f + (float)j) : (float)s_x[j];
  }
}

// ---------------------------------------------------------------- launch
extern "C" void kernel_launch(void* const* d_in, const int* in_sizes, int n_in,
                              void* d_out, int out_size, void* d_ws, size_t ws_size,
                              hipStream_t stream) {
  const float* log_mu = (const float*)d_in[0];
  const float* y      = (const float*)d_in[1];
  const float* t      = (const float*)d_in[2];
  const float* x_init = (const float*)d_in[3];
  float* out = (float*)d_out;
  int n = in_sizes[1];

  const size_t stats_bytes    = (size_t)NST * NBINS * sizeof(float);       // 28 KB
  const size_t partials_bytes = (size_t)BIN_BLOCKS * NST * NBINS * sizeof(float);

  if (d_ws && ws_size >= stats_bytes + partials_bytes) {
    float* stats    = (float*)d_ws;
    float* partials = (float*)((char*)d_ws + stats_bytes);
    bin_kernel<true><<<BIN_BLOCKS, BIN_THREADS, 0, stream>>>(y, t, n, partials);
    reduce_kernel<<<(NST * NBINS + 255) / 256, 256, 0, stream>>>(partials, stats);
    gn_kernel<false><<<1, ST, 0, stream>>>(stats, nullptr, nullptr, n,
                                           log_mu, x_init, out);
  } else if (d_ws && ws_size >= stats_bytes) {
    float* stats = (float*)d_ws;
    zero_stats<<<(NST * NBINS + 255) / 256, 256, 0, stream>>>(stats);
    bin_kernel<false><<<BIN_BLOCKS, BIN_THREADS, 0, stream>>>(y, t, n, stats);
    gn_kernel<false><<<1, ST, 0, stream>>>(stats, nullptr, nullptr, n,
                                           log_mu, x_init, out);
  } else {
    gn_kernel<true><<<1, ST, 0, stream>>>(nullptr, y, t, n,
                                          log_mu, x_init, out);
  }
}

// Round 6
// 195.336 us; speedup vs baseline: 1.5280x; 1.4137x over previous
//
#include <hip/hip_runtime.h>
#include <math.h>

// Binned-sufficient-statistics Newton solver, wave64 edition.
//  - bin_kernel: (t,y) -> 1024 fine bins x 7 fp32 stats (28 KB, LDS atomics).
//  - gn_kernel: 1 block x 64 threads. Fine bins collapsed to 64 coarse bins
//    (one per lane, 4th-order Taylor). Full-Newton + Armijo, all reductions
//    via __shfl_xor butterflies, Phase B redundant on all lanes. No LDS, no
//    __syncthreads, no runtime-indexed arrays.
//  R6: reverted R5's hipMemsetAsync (suspected graph-capture crash) back to
//  the known-good zero_stats kernel.

#define FBINS 1024
#define NST   7
#define TMAXF 5.0f
#define BIN_BLOCKS  256
#define BIN_THREADS 256
#define CB    64
#define CPL   (FBINS / CB)   // 16 fine bins per coarse bin

// ---------------------------------------------------------------- fast fp64 math
__device__ __forceinline__ double fexp(double x) {
  x = fmin(fmax(x, -708.0), 700.0);
  const double L2E   = 1.4426950408889634074;
  const double LN2HI = 6.93147180369123816490e-01;
  const double LN2LO = 1.90821492927058770002e-10;
  double fn = rint(x * L2E);
  double r  = fma(-fn, LN2HI, x);
  r = fma(-fn, LN2LO, r);
  double p = 2.505210838544172e-8;            // 1/11!
  p = fma(p, r, 2.755731922398589e-7);
  p = fma(p, r, 2.7557319223985893e-6);
  p = fma(p, r, 2.48015873015873e-5);
  p = fma(p, r, 1.984126984126984e-4);
  p = fma(p, r, 1.3888888888888889e-3);
  p = fma(p, r, 8.333333333333333e-3);
  p = fma(p, r, 4.1666666666666664e-2);
  p = fma(p, r, 1.6666666666666666e-1);
  p = fma(p, r, 0.5);
  p = fma(p, r, 1.0);
  p = fma(p, r, 1.0);
  long long n = (long long)fn;
  double s = __longlong_as_double((n + 1023LL) << 52);
  return p * s;
}

__device__ __forceinline__ double flog_ge1(double w) {  // w >= 1
  long long bits = __double_as_longlong(w);
  int k = (int)((bits >> 52) & 0x7FF) - 1023;
  double m = __longlong_as_double((bits & 0xFFFFFFFFFFFFFLL) | 0x3FF0000000000000LL);
  if (m > 1.4142135623730951) { m *= 0.5; k += 1; }
  double t  = (m - 1.0) / (m + 1.0);
  double t2 = t * t;
  double p = 1.0 / 13.0;
  p = fma(p, t2, 1.0 / 11.0);
  p = fma(p, t2, 1.0 / 9.0);
  p = fma(p, t2, 1.0 / 7.0);
  p = fma(p, t2, 0.2);
  p = fma(p, t2, 1.0 / 3.0);
  p = fma(p, t2, 1.0);
  p = 2.0 * t * p;
  return fma((double)k, 6.93147180559945309417e-01, p);
}

__device__ __forceinline__ double sp_fast(double u)  { return flog_ge1(1.0 + fexp(u)); }
__device__ __forceinline__ double sig_fast(double u) { return 1.0 / (1.0 + fexp(-u)); }

// butterfly: every lane ends with the full 64-lane sum (bitwise-uniform)
__device__ __forceinline__ double bred(double v) {
  for (int m = 1; m < 64; m <<= 1) v += __shfl_xor(v, m, 64);
  return v;
}

// ---------------------------------------------------------------- binning
__global__ void zero_stats(float* __restrict__ s) {
  int i = blockIdx.x * blockDim.x + threadIdx.x;
  if (i < NST * FBINS) s[i] = 0.0f;
}

__device__ __forceinline__ void bin_point(float* sb, float ti, float yi) {
  int b = (int)(ti * ((float)FBINS / TMAXF));
  b = b < 0 ? 0 : (b > FBINS - 1 ? FBINS - 1 : b);
  float c  = (b + 0.5f) * (TMAXF / (float)FBINS);
  float d  = ti - c;
  float d2 = d * d;
  atomicAdd(&sb[0 * FBINS + b], 1.0f);
  atomicAdd(&sb[1 * FBINS + b], d);
  atomicAdd(&sb[2 * FBINS + b], d2);
  atomicAdd(&sb[3 * FBINS + b], d2 * d);
  atomicAdd(&sb[4 * FBINS + b], yi);
  atomicAdd(&sb[5 * FBINS + b], yi * d);
  atomicAdd(&sb[6 * FBINS + b], yi * d2);
}

__global__ void bin_kernel(const float* __restrict__ y, const float* __restrict__ t,
                           int n, float* __restrict__ stats) {
  __shared__ float sb[NST * FBINS];
  for (int i = threadIdx.x; i < NST * FBINS; i += blockDim.x) sb[i] = 0.0f;
  __syncthreads();
  int gtid = blockIdx.x * blockDim.x + threadIdx.x;
  int nt   = gridDim.x * blockDim.x;
  int nv   = n >> 2;
  const float4* t4 = (const float4*)t;
  const float4* y4 = (const float4*)y;
  for (int i = gtid; i < nv; i += nt) {
    float4 tv = t4[i], yv = y4[i];
    bin_point(sb, tv.x, yv.x);
    bin_point(sb, tv.y, yv.y);
    bin_point(sb, tv.z, yv.z);
    bin_point(sb, tv.w, yv.w);
  }
  for (int i = (nv << 2) + gtid; i < n; i += nt) bin_point(sb, t[i], y[i]);
  __syncthreads();
  for (int i = threadIdx.x; i < NST * FBINS; i += blockDim.x) {
    float v = sb[i];
    if (v != 0.0f) atomicAdd(&stats[i], v);
  }
}

// ---------------------------------------------------------------- solver
template <bool FUSED>
__global__ __launch_bounds__(64)
void gn_kernel(const float* __restrict__ stats_g,
               const float* __restrict__ yv, const float* __restrict__ tv, int n,
               const float* __restrict__ log_mu_p,
               const float* __restrict__ x_init_p,
               float* __restrict__ out) {
  const int lane = threadIdx.x;

  __shared__ float sbin[FUSED ? NST * FBINS : 1];
  const float* stats = stats_g;
  if (FUSED) {   // safety net only (never taken when ws >= 28 KB)
    for (int i = lane; i < NST * FBINS; i += 64) sbin[i] = 0.0f;
    __syncthreads();
    for (int i = lane; i < n; i += 64) bin_point(sbin, tv[i], yv[i]);
    __syncthreads();
    stats = sbin;
  }

  // ---- collapse 16 fine bins -> 1 coarse bin per lane (4th-order stats) ----
  const double hf = 5.0 / 1024.0;          // exact in fp64/fp32
  double cn = 0, cb1 = 0, cb2 = 0, cb3 = 0, cb4 = 0;
  double cy = 0, cy1 = 0, cy2 = 0, cy3 = 0;
  const int base = lane * CPL;
#pragma unroll
  for (int i = 0; i < CPL; ++i) {
    double nf = (double)stats[0 * FBINS + base + i];
    double d1 = (double)stats[1 * FBINS + base + i];
    double d2 = (double)stats[2 * FBINS + base + i];
    double d3 = (double)stats[3 * FBINS + base + i];
    double yf = (double)stats[4 * FBINS + base + i];
    double y1 = (double)stats[5 * FBINS + base + i];
    double y2 = (double)stats[6 * FBINS + base + i];
    double dl  = ((double)i - 7.5) * hf;   // fine center - coarse center, exact
    double dl2 = dl * dl, dl3 = dl2 * dl, dl4 = dl2 * dl2;
    cn  += nf;
    cb1 += d1 + dl * nf;
    cb2 += d2 + 2.0 * dl * d1 + dl2 * nf;
    cb3 += d3 + 3.0 * dl * d2 + 3.0 * dl2 * d1 + dl3 * nf;
    cb4 += 4.0 * dl * d3 + 6.0 * dl2 * d2 + 4.0 * dl3 * d1 + dl4 * nf;
    cy  += yf;
    cy1 += y1 + dl * yf;
    cy2 += y2 + 2.0 * dl * y1 + dl2 * yf;
    cy3 += 3.0 * dl * y2 + 3.0 * dl2 * y1 + dl3 * yf;
  }
  const double cc = (double)(base + 8) * hf;   // coarse bin center, exact

  // ---- canary: total count ----
  {
    double tot = bred(cn);
    if (fabs(tot - (double)n) > (double)n * 1e-3 + 1.0) {
      if (lane == 0) for (int j = 0; j < 4; ++j) out[j] = 20.0f + (float)j;
      return;
    }
  }

  // ---- init (all lanes redundantly; uniform) ----
  const double mu = exp((double)log_mu_p[0]);
  double u0, u1, u2, u3;
  {
    double v0 = fmax((double)x_init_p[0], 1e-3);
    double v1 = fmax((double)x_init_p[1], 1e-3);
    double v2 = fmax((double)x_init_p[2], 1e-3);
    double v3 = fmax((double)x_init_p[3], 1e-3);
    u0 = log(exp(v0) - 1.0 + 1e-8);
    u1 = log(exp(v1) - 1.0 + 1e-8);
    u2 = log(exp(v2) - 1.0 + 1e-8);
    u3 = log(exp(v3) - 1.0 + 1e-8);
  }
  double x0 = sp_fast(u0), x1 = sp_fast(u1), x2 = sp_fast(u2), x3 = sp_fast(u3);

  for (int iter = 0; iter < 300; ++iter) {
    // ---- Phase A: 15 moments (1 coarse bin per lane + butterflies) ----
    double l0 = x2, l1 = x3;
    double E0 = fexp(-l0 * cc), E1 = fexp(-l1 * cc);
    double AA[3] = {E0 * E0, E0 * E1, E1 * E1};
    double MM[3] = {2.0 * l0, l0 + l1, 2.0 * l1};
    double mom[15];
#pragma unroll
    for (int q = 0; q < 3; ++q) {
      double m  = MM[q];
      double q0 = cn + m * (-cb1 + m * (0.5 * cb2 + m * (-(1.0/6.0) * cb3 + m * (1.0/24.0) * cb4)));
      double q1 = cb1 + m * (-cb2 + m * (0.5 * cb3 - m * (1.0/6.0) * cb4));
      double q2 = cb2 + m * (-cb3 + m * 0.5 * cb4);
      mom[q * 3 + 0] = AA[q] * q0;
      mom[q * 3 + 1] = AA[q] * (cc * q0 + q1);
      mom[q * 3 + 2] = AA[q] * (cc * (cc * q0 + 2.0 * q1) + q2);
    }
    {
      double r0 = cy + l0 * (-cy1 + l0 * (0.5 * cy2 - l0 * (1.0/6.0) * cy3));
      double r1 = cy1 + l0 * (-cy2 + 0.5 * l0 * cy3);
      double r2 = cy2 - l0 * cy3;
      mom[9]  = E0 * r0;
      mom[10] = E0 * (cc * r0 + r1);
      mom[11] = E0 * (cc * (cc * r0 + 2.0 * r1) + r2);
      r0 = cy + l1 * (-cy1 + l1 * (0.5 * cy2 - l1 * (1.0/6.0) * cy3));
      r1 = cy1 + l1 * (-cy2 + 0.5 * l1 * cy3);
      r2 = cy2 - l1 * cy3;
      mom[12] = E1 * r0;
      mom[13] = E1 * (cc * r0 + r1);
      mom[14] = E1 * (cc * (cc * r0 + 2.0 * r1) + r2);
    }
#pragma unroll
    for (int k = 0; k < 15; ++k) mom[k] = bred(mom[k]);

    double Sa = mom[0],  T1a = mom[1],  T2a = mom[2];
    double Sab= mom[3],  T1ab= mom[4],  T2ab= mom[5];
    double Sb = mom[6],  T1b = mom[7],  T2b = mom[8];
    double Y0a= mom[9],  Y1a = mom[10], Y2a = mom[11];
    double Y0b= mom[12], Y1b = mom[13], Y2b = mom[14];

    // ---- Phase B: Newton system (all lanes redundantly) ----
    double sd0 = sig_fast(u0), sd1 = sig_fast(u1), sd2 = sig_fast(u2), sd3 = sig_fast(u3);
    double sp0 = sd0 * (1.0 - sd0), sp1 = sd1 * (1.0 - sd1);
    double sp2 = sd2 * (1.0 - sd2), sp3 = sd3 * (1.0 - sd3);
    double c0 = x0, c1 = x1;

    double gx0 = -Y0a + c0 * Sa  + c1 * Sab;
    double gx1 = -Y0b + c0 * Sab + c1 * Sb;
    double gx2 = c0 * (Y1a - c0 * T1a  - c1 * T1ab);
    double gx3 = c1 * (Y1b - c0 * T1ab - c1 * T1b);
    double g0 = (gx0 + mu * x0) * sd0;
    double g1 = (gx1 + mu * x1) * sd1;
    double g2 = (gx2 + mu * x2) * sd2;
    double g3 = (gx3 + mu * x3) * sd3;

    double Hx[4][4];
    Hx[0][0] = Sa;   Hx[0][1] = Sab;
    Hx[0][2] = Y1a - 2.0 * c0 * T1a - c1 * T1ab;
    Hx[0][3] = -c1 * T1ab;
    Hx[1][1] = Sb;   Hx[1][2] = -c0 * T1ab;
    Hx[1][3] = Y1b - c0 * T1ab - 2.0 * c1 * T1b;
    Hx[2][2] = -c0 * Y2a + 2.0 * c0 * c0 * T2a + c0 * c1 * T2ab;
    Hx[2][3] = c0 * c1 * T2ab;
    Hx[3][3] = -c1 * Y2b + c0 * c1 * T2ab + 2.0 * c1 * c1 * T2b;
#pragma unroll
    for (int i = 1; i < 4; ++i)
#pragma unroll
      for (int j = 0; j < i; ++j) Hx[i][j] = Hx[j][i];

    double sdv[4] = {sd0, sd1, sd2, sd3};
    double spv[4] = {sp0, sp1, sp2, sp3};
    double gxv[4] = {gx0 + mu * x0, gx1 + mu * x1, gx2 + mu * x2, gx3 + mu * x3};
    double gv[4]  = {g0, g1, g2, g3};

    double H[4][5];
#pragma unroll
    for (int i = 0; i < 4; ++i) {
#pragma unroll
      for (int j = 0; j < 4; ++j)
        H[i][j] = sdv[i] * sdv[j] * (Hx[i][j] + (i == j ? mu : 0.0));
      H[i][i] += gxv[i] * spv[i] + 1e-7;
      H[i][4] = -gv[i];
    }
    // unpivoted elimination (constant indices -> registers)
#pragma unroll
    for (int col = 0; col < 4; ++col) {
      double inv = 1.0 / H[col][col];
#pragma unroll
      for (int rr = 0; rr < 4; ++rr) {
        if (rr > col) {
          double f = H[rr][col] * inv;
#pragma unroll
          for (int j = 0; j < 5; ++j) if (j >= col) H[rr][j] -= f * H[col][j];
        }
      }
    }
    double du[4];
#pragma unroll
    for (int i = 3; i >= 0; --i) {
      double s = H[i][4];
#pragma unroll
      for (int j = 0; j < 4; ++j) if (j > i) s -= H[i][j] * du[j];
      du[i] = s / H[i][i];
    }
    double gd = gv[0]*du[0] + gv[1]*du[1] + gv[2]*du[2] + gv[3]*du[3];
    bool bad = !(isfinite(du[0]) && isfinite(du[1]) &&
                 isfinite(du[2]) && isfinite(du[3])) || !(gd < 0.0);
    if (bad) {   // GN fallback (PD)
      double Jxx[4][4];
      Jxx[0][0] = Sa;            Jxx[0][1] = Sab;
      Jxx[0][2] = -c0 * T1a;     Jxx[0][3] = -c1 * T1ab;
      Jxx[1][1] = Sb;            Jxx[1][2] = -c0 * T1ab;  Jxx[1][3] = -c1 * T1b;
      Jxx[2][2] = c0 * c0 * T2a; Jxx[2][3] = c0 * c1 * T2ab;
      Jxx[3][3] = c1 * c1 * T2b;
#pragma unroll
      for (int i = 1; i < 4; ++i)
#pragma unroll
        for (int j = 0; j < i; ++j) Jxx[i][j] = Jxx[j][i];
#pragma unroll
      for (int i = 0; i < 4; ++i) {
#pragma unroll
        for (int j = 0; j < 4; ++j) H[i][j] = sdv[i] * sdv[j] * Jxx[i][j];
        H[i][i] += mu + 1e-7;
        H[i][4] = -gv[i];
      }
#pragma unroll
      for (int col = 0; col < 4; ++col) {
        double inv = 1.0 / H[col][col];
#pragma unroll
        for (int rr = 0; rr < 4; ++rr) {
          if (rr > col) {
            double f = H[rr][col] * inv;
#pragma unroll
            for (int j = 0; j < 5; ++j) if (j >= col) H[rr][j] -= f * H[col][j];
          }
        }
      }
#pragma unroll
      for (int i = 3; i >= 0; --i) {
        double s = H[i][4];
#pragma unroll
        for (int j = 0; j < 4; ++j) if (j > i) s -= H[i][j] * du[j];
        du[i] = s / H[i][i];
      }
      gd = gv[0]*du[0] + gv[1]*du[1] + gv[2]*du[2] + gv[3]*du[3];
      if (!(gd < 0.0)) {
        du[0] = -gv[0]; du[1] = -gv[1]; du[2] = -gv[2]; du[3] = -gv[3];
        gd = -(gv[0]*gv[0] + gv[1]*gv[1] + gv[2]*gv[2] + gv[3]*gv[3]);
      }
    }

    double loss = -2.0*c0*Y0a - 2.0*c1*Y0b
                + c0*c0*Sa + 2.0*c0*c1*Sab + c1*c1*Sb
                + mu * (x0*x0 + x1*x1 + x2*x2 + x3*x3);

    // grind-stopper: Newton decrement below fp64 loss resolution -> converged
    if (!(fabs(gd) > 1e-13 * fabs(loss))) break;

    double nrm = sqrt(du[0]*du[0] + du[1]*du[1] + du[2]*du[2] + du[3]*du[3]);

    // ---- Phase C: Armijo backtracking (uniform across lanes) ----
    double step = 1.0;
    bool done = false, accepted = false;
    for (int k = 0; k < 25; ++k) {
      double n0 = u0 + step * du[0], n1 = u1 + step * du[1];
      double n2 = u2 + step * du[2], n3 = u3 + step * du[3];
      double c0p = sp_fast(n0), c1p = sp_fast(n1);
      double l0p = sp_fast(n2), l1p = sp_fast(n3);
      double F0 = fexp(-l0p * cc), F1 = fexp(-l1p * cc);
      double BB[3] = {F0 * F0, F0 * F1, F1 * F1};
      double mm[3] = {2.0 * l0p, l0p + l1p, 2.0 * l1p};
      double a5[5];
#pragma unroll
      for (int q = 0; q < 3; ++q) {
        double m  = mm[q];
        double q0 = cn + m * (-cb1 + m * (0.5 * cb2 + m * (-(1.0/6.0) * cb3 + m * (1.0/24.0) * cb4)));
        a5[q] = BB[q] * q0;
      }
      a5[3] = F0 * (cy + l0p * (-cy1 + l0p * (0.5 * cy2 - l0p * (1.0/6.0) * cy3)));
      a5[4] = F1 * (cy + l1p * (-cy1 + l1p * (0.5 * cy2 - l1p * (1.0/6.0) * cy3)));
#pragma unroll
      for (int j = 0; j < 5; ++j) a5[j] = bred(a5[j]);

      double loss_new = -2.0*c0p*a5[3] - 2.0*c1p*a5[4]
                      + c0p*c0p*a5[0] + 2.0*c0p*c1p*a5[1] + c1p*c1p*a5[2]
                      + mu * (c0p*c0p + c1p*c1p + l0p*l0p + l1p*l1p);
      bool ok = (loss_new <= loss - 1e-4 * step * gd);   // NaN -> reject
      if (ok) {
        u0 = n0; u1 = n1; u2 = n2; u3 = n3;
        x0 = c0p; x1 = c1p; x2 = l0p; x3 = l1p;
        if (step * nrm < 1e-9) done = true;
        accepted = true;
        break;
      }
      step *= 0.5;
    }
    if (!accepted) {   // forced exit after 25 halvings (step already halved 25x)
      u0 += step * du[0]; u1 += step * du[1];
      u2 += step * du[2]; u3 += step * du[3];
      x0 = sp_fast(u0); x1 = sp_fast(u1); x2 = sp_fast(u2); x3 = sp_fast(u3);
      if (step * nrm < 1e-9) done = true;
    }
    if (done) break;
  }

  if (lane == 0) {
    bool bad = !(isfinite(x0) && isfinite(x1) && isfinite(x2) && isfinite(x3));
    out[0] = bad ? 50.0f : (float)x0;
    out[1] = bad ? 51.0f : (float)x1;
    out[2] = bad ? 52.0f : (float)x2;
    out[3] = bad ? 53.0f : (float)x3;
  }
}

// ---------------------------------------------------------------- launch
extern "C" void kernel_launch(void* const* d_in, const int* in_sizes, int n_in,
                              void* d_out, int out_size, void* d_ws, size_t ws_size,
                              hipStream_t stream) {
  const float* log_mu = (const float*)d_in[0];
  const float* y      = (const float*)d_in[1];
  const float* t      = (const float*)d_in[2];
  const float* x_init = (const float*)d_in[3];
  float* out = (float*)d_out;
  int n = in_sizes[1];

  const size_t stats_bytes = (size_t)NST * FBINS * sizeof(float);   // 28 KB
  if (d_ws && ws_size >= stats_bytes) {
    float* stats = (float*)d_ws;
    zero_stats<<<(NST * FBINS + 255) / 256, 256, 0, stream>>>(stats);
    bin_kernel<<<BIN_BLOCKS, BIN_THREADS, 0, stream>>>(y, t, n, stats);
    gn_kernel<false><<<1, 64, 0, stream>>>(stats, nullptr, nullptr, n,
                                           log_mu, x_init, out);
  } else {
    gn_kernel<true><<<1, 64, 0, stream>>>(nullptr, y, t, n,
                                          log_mu, x_init, out);
  }
}